// Round 12
// baseline (2005.195 us; speedup 1.0000x reference)
//
#include <hip/hip_runtime.h>
#include <math.h>

#define NEGV (-100000.0f)
constexpr int Bn = 64, Sn = 512, En = 256, Hn = 256, HIDn = 512, Tn = 9;
constexpr int START_T = Tn - 2, STOP_T = Tn - 1;
constexpr int Mn = Bn * Sn; // 32768 rows

typedef unsigned int u32;
typedef unsigned short u16;
typedef unsigned long long u64;
typedef short short8 __attribute__((ext_vector_type(8)));
typedef float f32x4 __attribute__((ext_vector_type(4)));
typedef int i32x4 __attribute__((ext_vector_type(4)));

__device__ __forceinline__ float sigf(float x) { return 1.0f / (1.0f + __expf(-x)); }
__device__ __forceinline__ float tanh_f(float x) { return 2.0f / (1.0f + __expf(-2.0f * x)) - 1.0f; }
__device__ __forceinline__ u16 f2bf(float f) {
  u32 u = __float_as_uint(f);
  return (u16)((u + 0x7fffu + ((u >> 16) & 1u)) >> 16);
}
__device__ __forceinline__ float bflo(u32 u) { return __uint_as_float(u << 16); }
__device__ __forceinline__ float bfhi(u32 u) { return __uint_as_float(u & 0xffff0000u); }
__device__ __forceinline__ float b2f(u16 v) { return __uint_as_float((u32)v << 16); }

// LDS-only workgroup barrier: does NOT drain vmcnt (global loads/stores stay in flight).
__device__ __forceinline__ void bar_lds() {
  __builtin_amdgcn_sched_barrier(0);
  asm volatile("s_waitcnt lgkmcnt(0)" ::: "memory");
  __builtin_amdgcn_s_barrier();
  __builtin_amdgcn_sched_barrier(0);
}

// ---------------- scales for int8 recurrent weights: one WAVE per gate-row ----------------
__global__ __launch_bounds__(256) void prep_scales(const float* __restrict__ whh0,
                                                   const float* __restrict__ whh1,
                                                   float* __restrict__ sw0, float* __restrict__ dqs0,
                                                   float* __restrict__ sw1, float* __restrict__ dqs1,
                                                   float* __restrict__ rsw0, float* __restrict__ rsw1) {
  const int gid = blockIdx.x * blockDim.x + threadIdx.x;
  const int row = gid >> 6;            // one wave per row
  const int lane = gid & 63;
  if (row >= 2048) return;
  float4 v0 = *reinterpret_cast<const float4*>(whh0 + (size_t)row * 256 + lane * 4);
  float4 v1 = *reinterpret_cast<const float4*>(whh1 + (size_t)row * 256 + lane * 4);
  float m0 = fmaxf(fmaxf(fabsf(v0.x), fabsf(v0.y)), fmaxf(fabsf(v0.z), fabsf(v0.w)));
  float m1 = fmaxf(fmaxf(fabsf(v1.x), fabsf(v1.y)), fmaxf(fabsf(v1.z), fabsf(v1.w)));
#pragma unroll
  for (int off = 32; off; off >>= 1) {
    m0 = fmaxf(m0, __shfl_xor(m0, off));
    m1 = fmaxf(m1, __shfl_xor(m1, off));
  }
  if (lane == 0) {
    m0 = fmaxf(m0, 1e-8f); m1 = fmaxf(m1, 1e-8f);
    sw0[row] = m0 / 127.f; dqs0[row] = m0 / (127.f * 127.f);
    sw1[row] = m1 / 127.f; dqs1[row] = m1 / (127.f * 127.f);
    rsw0[row] = 127.f / m0; rsw1[row] = 127.f / m1;
  }
}

// ---------------- prep: wih/fcw -> bf16 MFMA B-frags; whh -> int8 MFMA B-frags ----------------
__global__ void prep_kernel(const float* __restrict__ wih0, const float* __restrict__ whh0,
                            const float* __restrict__ bih0, const float* __restrict__ bhh0,
                            const float* __restrict__ wih1, const float* __restrict__ whh1,
                            const float* __restrict__ bih1, const float* __restrict__ bhh1,
                            const float* __restrict__ fcw,
                            u16* __restrict__ wifrag0, u16* __restrict__ wifrag1,
                            char* __restrict__ wq0, char* __restrict__ wq1,
                            const float* __restrict__ rsw0, const float* __restrict__ rsw1,
                            float* __restrict__ bias0, float* __restrict__ bias1,
                            u16* __restrict__ fcfrag) {
  int tid = blockIdx.x * blockDim.x + threadIdx.x;
  int nth = gridDim.x * blockDim.x;
  for (int idx = tid; idx < 524288; idx += nth) {
    int j = idx & 7, lane = (idx >> 3) & 63, ks = (idx >> 9) & 7,
        w2 = (idx >> 12) & 3, nb = (idx >> 14) & 15, d = (idx >> 18) & 1;
    int n = nb * 64 + w2 * 16 + (lane & 15);
    int k = ks * 32 + ((lane >> 4) & 3) * 8 + j;
    wifrag0[idx] = f2bf(wih0[(d * 1024 + n) * 256 + k]);
  }
  for (int idx = tid; idx < 1048576; idx += nth) {
    int j = idx & 7, lane = (idx >> 3) & 63, ks = (idx >> 9) & 15,
        w2 = (idx >> 13) & 3, nb = (idx >> 15) & 15, d = (idx >> 19) & 1;
    int n = nb * 64 + w2 * 16 + (lane & 15);
    int k = ks * 32 + ((lane >> 4) & 3) * 8 + j;
    wifrag1[idx] = f2bf(wih1[(d * 1024 + n) * 512 + k]);
  }
  // whh int8 frags: [d][w][q][kt][lane][j]
  for (int idx = tid; idx < 524288; idx += nth) {
    int j = idx & 15, lane = (idx >> 4) & 63, kt = (idx >> 10) & 3,
        q = (idx >> 12) & 7, wv = (idx >> 15) & 7, d = (idx >> 18) & 1;
    int nt = q * 8 + wv;
    int n = nt * 16 + (lane & 15);
    int k = kt * 64 + ((lane >> 4) & 3) * 16 + j;
    int row = d * 1024 + n;
    float v0 = whh0[(size_t)row * 256 + k] * rsw0[row];
    float v1 = whh1[(size_t)row * 256 + k] * rsw1[row];
    wq0[idx] = (char)(int)fminf(fmaxf(rintf(v0), -127.f), 127.f);
    wq1[idx] = (char)(int)fminf(fmaxf(rintf(v1), -127.f), 127.f);
  }
  // fc frags: 16*64*8 = 8192 u16 (tags >= 9 zero-padded)
  for (int idx = tid; idx < 8192; idx += nth) {
    int j = idx & 7, lane = (idx >> 3) & 63, ks = (idx >> 9) & 15;
    int tag = lane & 15;
    int k = ks * 32 + ((lane >> 4) & 3) * 8 + j;
    fcfrag[idx] = (tag < Tn) ? f2bf(fcw[(size_t)tag * HIDn + k]) : (u16)0;
  }
  for (int idx = tid; idx < 2 * 1024; idx += nth) {
    bias0[idx] = bih0[idx] + bhh0[idx];
    bias1[idx] = bih1[idx] + bhh1[idx];
  }
}

// ---------------- MFMA input-projection GEMM -> gate-packed gx2[dir][m][unit][gate] ----------------
// v3: B-frag stream double-buffered across the 16 (ub,gate) iterations — iteration i+1's
// 16 global loads issue BEFORE iteration i's 64 MFMAs, hiding L2/HBM latency in-wave.
// Gate-inner order + packed uint2 epilogue (one coalesced 8B store per (m,unit)).
template <int KS, bool GATHER>   // KS = K/32
__global__ __launch_bounds__(256, 2) void gemm_ih(
    const void* __restrict__ xsrc_v,   // GATHER: fp32 emb; else bf16 rows [M][512]
    const int* __restrict__ sent,
    const uint4* __restrict__ wifrag,  // [2][16][4][KS][64] uint4
    const float* __restrict__ bias,    // [2][1024]
    u16* __restrict__ gx2)             // [2*M][256][4] bf16
{
  constexpr int K = KS * 32;
  constexpr int PITCH = K + 8;
  __shared__ u16 As[64][PITCH];
  const int tid = threadIdx.x;
  const int l = tid & 63;
  const int w = tid >> 6;
  const int col = l & 15;
  const int quad = (l >> 4) & 3;
  const int m0 = blockIdx.x * 64;
  const int dir = blockIdx.y;

  {
    const int lr = tid >> 2, lq = tid & 3;
    if constexpr (GATHER) {
      const float4* xrow = reinterpret_cast<const float4*>(
          (const float*)xsrc_v + (size_t)sent[m0 + lr] * 256) + lq * 16;
      u32* dst = reinterpret_cast<u32*>(&As[lr][lq * 64]);
#pragma unroll
      for (int i = 0; i < 16; ++i) {
        float4 v = xrow[i];
        dst[i * 2 + 0] = (u32)f2bf(v.x) | ((u32)f2bf(v.y) << 16);
        dst[i * 2 + 1] = (u32)f2bf(v.z) | ((u32)f2bf(v.w) << 16);
      }
    } else {
      const uint4* xrow = reinterpret_cast<const uint4*>(
          (const u16*)xsrc_v + (size_t)(m0 + lr) * 512) + lq * 16;
      uint4* dst = reinterpret_cast<uint4*>(&As[lr][lq * 128]);
#pragma unroll
      for (int i = 0; i < 16; ++i) dst[i] = xrow[i];
    }
  }
  __syncthreads();

  const uint4* wfd = wifrag + (size_t)dir * 16 * 4 * KS * 64;

  u32 pk0[4][4];   // gates 0,1 packed (i | f<<16) per [mt][r]
  u32 pk1[4][4];   // gates 2,3 packed (g | o<<16) per [mt][r]

  // it = ub*4 + gate; nb = gate*4 + ub
  auto bload = [&](uint4 (&buf)[KS], int it) {
    const int ub = it >> 2, gate = it & 3;
    const int nb = gate * 4 + ub;
    const uint4* bp = wfd + ((size_t)(nb * 4 + w) * KS) * 64 + l;
#pragma unroll
    for (int ks = 0; ks < KS; ++ks) buf[ks] = bp[ks * 64];
  };

  auto bodyc = [&](uint4 (&cur)[KS], int it) {
    f32x4 acc[4];
#pragma unroll
    for (int mt = 0; mt < 4; ++mt) acc[mt] = (f32x4){0.f, 0.f, 0.f, 0.f};
#pragma unroll
    for (int ks = 0; ks < KS; ++ks) {
      short8 b8 = __builtin_bit_cast(short8, cur[ks]);
#pragma unroll
      for (int mt = 0; mt < 4; ++mt) {
        uint4 av = *reinterpret_cast<const uint4*>(&As[mt * 16 + col][ks * 32 + quad * 8]);
        acc[mt] = __builtin_amdgcn_mfma_f32_16x16x32_bf16(
            __builtin_bit_cast(short8, av), b8, acc[mt], 0, 0, 0);
      }
    }
    const int ub = it >> 2, gate = it & 3;
    const int n = (gate * 4 + ub) * 64 + w * 16 + col;
    const float bv = bias[dir * 1024 + n];
#pragma unroll
    for (int mt = 0; mt < 4; ++mt) {
#pragma unroll
      for (int r = 0; r < 4; ++r) {
        u32 val = (u32)f2bf(acc[mt][r] + bv);
        if (gate == 0)      pk0[mt][r] = val;
        else if (gate == 1) pk0[mt][r] |= val << 16;
        else if (gate == 2) pk1[mt][r] = val;
        else                pk1[mt][r] |= val << 16;
      }
    }
    if (gate == 3) {
      const int u = ub * 64 + w * 16 + col;
#pragma unroll
      for (int mt = 0; mt < 4; ++mt) {
#pragma unroll
        for (int r = 0; r < 4; ++r) {
          const int m = m0 + mt * 16 + quad * 4 + r;
          *reinterpret_cast<uint2*>(gx2 + ((size_t)(dir * Mn + m) * 256 + u) * 4) =
              (uint2){pk0[mt][r], pk1[mt][r]};
        }
      }
    }
  };

  uint4 bufA[KS], bufB[KS];
  bload(bufA, 0);
#pragma unroll 1
  for (int itp = 0; itp < 8; ++itp) {
    bload(bufB, itp * 2 + 1);        // prefetch odd iter (hides under even compute)
    bodyc(bufA, itp * 2);
    if (itp < 7) bload(bufA, itp * 2 + 2);  // prefetch next even (hides under odd compute)
    bodyc(bufB, itp * 2 + 1);
  }
}

// ---------------- MFMA recurrence v12 (proven 531 us): 2-row blocks, wave-local handoff ----
__global__ __launch_bounds__(512, 2) void lstm_recur_v12(
    const i32x4* __restrict__ wq,     // [2][8][8][4][64] i32x4
    const float* __restrict__ dqs,    // [2][1024]
    const u16* __restrict__ gx2,      // [2*Mn][256][4] bf16
    u16* __restrict__ out)            // [B][S][512] bf16
{
  __shared__ char Ah8[2][2][288];     // dbuf int8 h tile [2 rows][256 units], padded pitch
  __shared__ int accW[8][2][32][4];   // per-wave raw i32 acc [wave][row][unit-idx][gate]
  const int tid = threadIdx.x;
  const int l = tid & 63;
  const int w = tid >> 6;             // wave 0..7
  const int col = l & 15;
  const int quad = (l >> 4) & 3;
  const int dir = blockIdx.x >> 5;
  const int bq = blockIdx.x & 31;

  // ---- int8 recurrent weights into registers: 32 x i32x4 per lane ----
  i32x4 bw[8][4];
  {
    const i32x4* wp = wq + ((size_t)dir * 8 + w) * 8 * 4 * 64;
#pragma unroll
    for (int q = 0; q < 8; ++q)
#pragma unroll
      for (int kt = 0; kt < 4; ++kt)
        bw[q][kt] = wp[(q * 4 + kt) * 64 + l];
  }

  // epilogue task for this lane: row r_ep (0..1), unit-idx ue (0..31) within wave w
  const int r_ep = l >> 5;
  const int ue = l & 31;
  const int e_ep = ue >> 4, c_ep = ue & 15;
  const int unit = e_ep * 128 + w * 16 + c_ep;

  float sc[4];
#pragma unroll
  for (int g = 0; g < 4; ++g)
    sc[g] = dqs[dir * 1024 + g * 256 + unit];

  const int mrow = bq * 2 + r_ep;
  const uint2* gp = reinterpret_cast<const uint2*>(gx2) +
                    (size_t)(dir * Mn + mrow * Sn) * 256 + unit;
  u16* op = out + (size_t)mrow * Sn * HIDn + dir * Hn + unit;

  float c_st = 0.f;

  for (int s = 0; s < Sn; ++s) {
    const int t = dir ? (Sn - 1 - s) : s;
    uint2 g2 = gp[(size_t)t * 256];   // in flight across phases (lgkm-only barriers)

    if (s > 0) {
      const int rb = (s + 1) & 1;
      i32x4 av[4];
#pragma unroll
      for (int kt = 0; kt < 4; ++kt)
        av[kt] = *reinterpret_cast<const i32x4*>(
            &Ah8[rb][col & 1][kt * 64 + quad * 16]);
      i32x4 acc[8];
#pragma unroll
      for (int q = 0; q < 8; ++q) acc[q] = (i32x4){0, 0, 0, 0};
#pragma unroll
      for (int kt = 0; kt < 4; ++kt)
#pragma unroll
        for (int q = 0; q < 8; ++q)
          acc[q] = __builtin_amdgcn_mfma_i32_16x16x64_i8(av[kt], bw[q][kt], acc[q], 0, 0, 0);
      // wave-local scatter: quad0 lanes hold C rows 0..3; rows 0,1 are the real batch rows
      if (quad == 0) {
#pragma unroll
        for (int e = 0; e < 2; ++e)
#pragma unroll
          for (int r = 0; r < 2; ++r) {
            i32x4 v = (i32x4){acc[0 + e][r], acc[2 + e][r], acc[4 + e][r], acc[6 + e][r]};
            *reinterpret_cast<i32x4*>(&accW[w][r][e * 16 + col][0]) = v;
          }
      }
      // no barrier: same-wave LDS RAW ordered by lgkmcnt (compiler-inserted)
    }

    float a0 = 0.f, a1 = 0.f, a2 = 0.f, a3 = 0.f;
    if (s > 0) {
      i32x4 q0 = *reinterpret_cast<const i32x4*>(&accW[w][r_ep][ue][0]);
      a0 = (float)q0[0] * sc[0];
      a1 = (float)q0[1] * sc[1];
      a2 = (float)q0[2] * sc[2];
      a3 = (float)q0[3] * sc[3];
    }
    float gi_ = a0 + b2f((u16)(g2.x & 0xffff));
    float gf_ = a1 + b2f((u16)(g2.x >> 16));
    float gg_ = a2 + b2f((u16)(g2.y & 0xffff));
    float go_ = a3 + b2f((u16)(g2.y >> 16));

    c_st = sigf(gf_) * c_st + sigf(gi_) * tanh_f(gg_);
    float h = sigf(go_) * tanh_f(c_st);

    Ah8[s & 1][r_ep][unit] = (char)(int)rintf(h * 127.f);
    op[(size_t)t * HIDn] = f2bf(h);
    bar_lds();   // ONE barrier: h tile visible to all waves; out store stays in flight
  }
}

// ---------------- FC via MFMA: feats[bs][tag] = out1[bs] . fcw[tag] + fcb ----------------
__global__ __launch_bounds__(256) void fc_mfma(const u16* __restrict__ out1,
                                               const uint4* __restrict__ fcfrag, // [16][64]
                                               const float* __restrict__ fcb,
                                               float* __restrict__ feats) {
  __shared__ u16 As[64][520];
  const int tid = threadIdx.x;
  const int l = tid & 63;
  const int w = tid >> 6;
  const int col = l & 15;
  const int quad = (l >> 4) & 3;
  const int m0 = blockIdx.x * 64;

  {
    const int lr = tid >> 2, lq = tid & 3;
    const uint4* xrow = reinterpret_cast<const uint4*>(
        out1 + (size_t)(m0 + lr) * 512) + lq * 16;
    uint4* dst = reinterpret_cast<uint4*>(&As[lr][lq * 128]);
#pragma unroll
    for (int i = 0; i < 16; ++i) dst[i] = xrow[i];
  }
  __syncthreads();

  uint4 bf[16];
#pragma unroll
  for (int ks = 0; ks < 16; ++ks) bf[ks] = fcfrag[ks * 64 + l];

  f32x4 acc = (f32x4){0.f, 0.f, 0.f, 0.f};
#pragma unroll
  for (int ks = 0; ks < 16; ++ks) {
    uint4 av = *reinterpret_cast<const uint4*>(&As[w * 16 + col][ks * 32 + quad * 8]);
    acc = __builtin_amdgcn_mfma_f32_16x16x32_bf16(
        __builtin_bit_cast(short8, av), __builtin_bit_cast(short8, bf[ks]), acc, 0, 0, 0);
  }

  if (col < Tn) {
    const float bv = fcb[col];
#pragma unroll
    for (int r = 0; r < 4; ++r) {
      int m = m0 + w * 16 + quad * 4 + r;
      feats[(size_t)m * Tn + col] = acc[r] + bv;
    }
  }
}

// ---------------- CRF forward + gold, one wave per batch ----------------
__global__ __launch_bounds__(64) void crf_kernel(const float* __restrict__ feats,
                                                 const int* __restrict__ tags,
                                                 const int* __restrict__ lens,
                                                 const float* __restrict__ trans,
                                                 float* __restrict__ scores) {
  const int b = blockIdx.x;
  const int j = threadIdx.x;
  const int jj = j < Tn ? j : Tn - 1;
  const int len = lens[b];

  float trc[Tn];
#pragma unroll
  for (int i = 0; i < Tn; ++i) trc[i] = trans[i * Tn + jj];
  const float trS = trans[jj * Tn + STOP_T];

  float alpha = (j == START_T) ? 0.0f : NEGV;
  const float* fb = feats + (size_t)b * Sn * Tn;

  for (int t = 0; t < Sn; ++t) {
    float f = (j < Tn) ? fb[t * Tn + j] : 0.0f;
    float v[Tn];
    float m = -3.0e38f;
#pragma unroll
    for (int i = 0; i < Tn; ++i) {
      float ai = __shfl(alpha, i);
      v[i] = ai + trc[i];
      m = fmaxf(m, v[i]);
    }
    float ssum = 0.0f;
#pragma unroll
    for (int i = 0; i < Tn; ++i) ssum += __expf(v[i] - m);
    float newa = m + __logf(ssum) + f;
    if (t < len && j < Tn) alpha = newa;
  }

  float val = (j < Tn) ? alpha + trS : -3.0e38f;
  float m = val;
#pragma unroll
  for (int off = 32; off; off >>= 1) m = fmaxf(m, __shfl_xor(m, off));
  float se = (j < Tn) ? __expf(val - m) : 0.0f;
#pragma unroll
  for (int off = 32; off; off >>= 1) se += __shfl_xor(se, off);
  float fscore = m + __logf(se);

  const int* tg = tags + b * Sn;
  float part = 0.0f;
  for (int q = 0; q < 8; ++q) {
    int s0 = j * 8 + q;
    if (s0 < Sn - 1 && (s0 + 1) < len) {
      int ta = tg[s0], tb = tg[s0 + 1];
      part += trans[ta * Tn + tb] + fb[s0 * Tn + tb];
    }
  }
#pragma unroll
  for (int off = 32; off; off >>= 1) part += __shfl_xor(part, off);

  if (j == 0) {
    int t0 = tg[0];
    int tl = tg[len - 1];
    float gold = trans[START_T * Tn + t0] + fb[0 * Tn + t0] + part + trans[tl * Tn + STOP_T];
    scores[b] = fscore - gold;
  }
}

__global__ void finalize_kernel(const float* __restrict__ scores, float* __restrict__ out) {
  int l = threadIdx.x;
  float v = scores[l];
#pragma unroll
  for (int off = 32; off; off >>= 1) v += __shfl_xor(v, off);
  if (l == 0) out[0] = v / 64.0f;
}

extern "C" void kernel_launch(void* const* d_in, const int* in_sizes, int n_in,
                              void* d_out, int out_size, void* d_ws, size_t ws_size,
                              hipStream_t stream) {
  const int* sent = (const int*)d_in[0];
  const int* tags = (const int*)d_in[1];
  const int* lens = (const int*)d_in[2];
  const float* emb = (const float*)d_in[3];
  const float* wih0 = (const float*)d_in[4];
  const float* whh0 = (const float*)d_in[5];
  const float* bih0 = (const float*)d_in[6];
  const float* bhh0 = (const float*)d_in[7];
  const float* wih1 = (const float*)d_in[8];
  const float* whh1 = (const float*)d_in[9];
  const float* bih1 = (const float*)d_in[10];
  const float* bhh1 = (const float*)d_in[11];
  const float* fcw = (const float*)d_in[12];
  const float* fcb = (const float*)d_in[13];
  const float* trans = (const float*)d_in[14];

  // workspace (~172 MB)
  char* ws = (char*)d_ws;
  u16* outb = (u16*)ws;                                  // 33,554,432 B
  u16* gx2 = (u16*)(ws + 33554432);                      // 134,217,728 B
  float* feats = (float*)gx2;                            // aliases gx2 (dead before fc)
  char* p = ws + 33554432 + 134217728;
  float* scores = (float*)p;            p += 256;
  float* bias0 = (float*)p;             p += 8192;
  float* bias1 = (float*)p;             p += 8192;
  u16* wifrag0 = (u16*)p;               p += 1048576;    // 524,288 u16
  u16* wifrag1 = (u16*)p;               p += 2097152;    // 1,048,576 u16
  char* wq0 = p;                        p += 524288;     // int8 whh frags layer0
  char* wq1 = p;                        p += 524288;     // int8 whh frags layer1
  float* sw0 = (float*)p;               p += 8192;
  float* dqs0 = (float*)p;              p += 8192;
  float* sw1 = (float*)p;               p += 8192;
  float* dqs1 = (float*)p;              p += 8192;
  float* rsw0 = (float*)p;              p += 8192;
  float* rsw1 = (float*)p;              p += 8192;
  u16* fcfrag = (u16*)p;                p += 16384;      // 8192 u16

  prep_scales<<<512, 256, 0, stream>>>(whh0, whh1, sw0, dqs0, sw1, dqs1, rsw0, rsw1);
  prep_kernel<<<2048, 256, 0, stream>>>(wih0, whh0, bih0, bhh0, wih1, whh1, bih1, bhh1, fcw,
                                        wifrag0, wifrag1, wq0, wq1, rsw0, rsw1, bias0, bias1,
                                        fcfrag);

  dim3 ggrid(Mn / 64, 2);
  gemm_ih<8, true><<<ggrid, 256, 0, stream>>>(emb, sent, (const uint4*)wifrag0, bias0, gx2);
  lstm_recur_v12<<<64, 512, 0, stream>>>((const i32x4*)wq0, dqs0, gx2, outb);
  gemm_ih<16, false><<<ggrid, 256, 0, stream>>>(outb, nullptr, (const uint4*)wifrag1, bias1, gx2);
  lstm_recur_v12<<<64, 512, 0, stream>>>((const i32x4*)wq1, dqs1, gx2, outb);

  fc_mfma<<<Mn / 64, 256, 0, stream>>>(outb, (const uint4*)fcfrag, fcb, feats);
  crf_kernel<<<Bn, 64, 0, stream>>>(feats, tags, lens, trans, scores);
  finalize_kernel<<<1, 64, 0, stream>>>(scores, (float*)d_out);
}

// Round 13
// 1983.523 us; speedup vs baseline: 1.0109x; 1.0109x over previous
//
#include <hip/hip_runtime.h>
#include <math.h>

#define NEGV (-100000.0f)
constexpr int Bn = 64, Sn = 512, En = 256, Hn = 256, HIDn = 512, Tn = 9;
constexpr int START_T = Tn - 2, STOP_T = Tn - 1;
constexpr int Mn = Bn * Sn; // 32768 rows

typedef unsigned int u32;
typedef unsigned short u16;
typedef unsigned long long u64;
typedef short short8 __attribute__((ext_vector_type(8)));
typedef float f32x4 __attribute__((ext_vector_type(4)));
typedef int i32x4 __attribute__((ext_vector_type(4)));

__device__ __forceinline__ float sigf(float x) { return 1.0f / (1.0f + __expf(-x)); }
__device__ __forceinline__ float tanh_f(float x) { return 2.0f / (1.0f + __expf(-2.0f * x)) - 1.0f; }
__device__ __forceinline__ u16 f2bf(float f) {
  u32 u = __float_as_uint(f);
  return (u16)((u + 0x7fffu + ((u >> 16) & 1u)) >> 16);
}
__device__ __forceinline__ float bflo(u32 u) { return __uint_as_float(u << 16); }
__device__ __forceinline__ float bfhi(u32 u) { return __uint_as_float(u & 0xffff0000u); }
__device__ __forceinline__ float b2f(u16 v) { return __uint_as_float((u32)v << 16); }

// LDS-only workgroup barrier: does NOT drain vmcnt (global loads/stores stay in flight).
__device__ __forceinline__ void bar_lds() {
  __builtin_amdgcn_sched_barrier(0);
  asm volatile("s_waitcnt lgkmcnt(0)" ::: "memory");
  __builtin_amdgcn_s_barrier();
  __builtin_amdgcn_sched_barrier(0);
}

// ---------------- scales for int8 recurrent weights: one WAVE per gate-row ----------------
__global__ __launch_bounds__(256) void prep_scales(const float* __restrict__ whh0,
                                                   const float* __restrict__ whh1,
                                                   float* __restrict__ sw0, float* __restrict__ dqs0,
                                                   float* __restrict__ sw1, float* __restrict__ dqs1,
                                                   float* __restrict__ rsw0, float* __restrict__ rsw1) {
  const int gid = blockIdx.x * blockDim.x + threadIdx.x;
  const int row = gid >> 6;            // one wave per row
  const int lane = gid & 63;
  if (row >= 2048) return;
  float4 v0 = *reinterpret_cast<const float4*>(whh0 + (size_t)row * 256 + lane * 4);
  float4 v1 = *reinterpret_cast<const float4*>(whh1 + (size_t)row * 256 + lane * 4);
  float m0 = fmaxf(fmaxf(fabsf(v0.x), fabsf(v0.y)), fmaxf(fabsf(v0.z), fabsf(v0.w)));
  float m1 = fmaxf(fmaxf(fabsf(v1.x), fabsf(v1.y)), fmaxf(fabsf(v1.z), fabsf(v1.w)));
#pragma unroll
  for (int off = 32; off; off >>= 1) {
    m0 = fmaxf(m0, __shfl_xor(m0, off));
    m1 = fmaxf(m1, __shfl_xor(m1, off));
  }
  if (lane == 0) {
    m0 = fmaxf(m0, 1e-8f); m1 = fmaxf(m1, 1e-8f);
    sw0[row] = m0 / 127.f; dqs0[row] = m0 / (127.f * 127.f);
    sw1[row] = m1 / 127.f; dqs1[row] = m1 / (127.f * 127.f);
    rsw0[row] = 127.f / m0; rsw1[row] = 127.f / m1;
  }
}

// ---------------- prep: wih/fcw -> bf16 MFMA B-frags; whh -> int8 MFMA B-frags ----------------
__global__ void prep_kernel(const float* __restrict__ wih0, const float* __restrict__ whh0,
                            const float* __restrict__ bih0, const float* __restrict__ bhh0,
                            const float* __restrict__ wih1, const float* __restrict__ whh1,
                            const float* __restrict__ bih1, const float* __restrict__ bhh1,
                            const float* __restrict__ fcw,
                            u16* __restrict__ wifrag0, u16* __restrict__ wifrag1,
                            char* __restrict__ wq0, char* __restrict__ wq1,
                            const float* __restrict__ rsw0, const float* __restrict__ rsw1,
                            float* __restrict__ bias0, float* __restrict__ bias1,
                            u16* __restrict__ fcfrag) {
  int tid = blockIdx.x * blockDim.x + threadIdx.x;
  int nth = gridDim.x * blockDim.x;
  for (int idx = tid; idx < 524288; idx += nth) {
    int j = idx & 7, lane = (idx >> 3) & 63, ks = (idx >> 9) & 7,
        w2 = (idx >> 12) & 3, nb = (idx >> 14) & 15, d = (idx >> 18) & 1;
    int n = nb * 64 + w2 * 16 + (lane & 15);
    int k = ks * 32 + ((lane >> 4) & 3) * 8 + j;
    wifrag0[idx] = f2bf(wih0[(d * 1024 + n) * 256 + k]);
  }
  for (int idx = tid; idx < 1048576; idx += nth) {
    int j = idx & 7, lane = (idx >> 3) & 63, ks = (idx >> 9) & 15,
        w2 = (idx >> 13) & 3, nb = (idx >> 15) & 15, d = (idx >> 19) & 1;
    int n = nb * 64 + w2 * 16 + (lane & 15);
    int k = ks * 32 + ((lane >> 4) & 3) * 8 + j;
    wifrag1[idx] = f2bf(wih1[(d * 1024 + n) * 512 + k]);
  }
  // whh int8 frags: [d][w][q][kt][lane][j]
  for (int idx = tid; idx < 524288; idx += nth) {
    int j = idx & 15, lane = (idx >> 4) & 63, kt = (idx >> 10) & 3,
        q = (idx >> 12) & 7, wv = (idx >> 15) & 7, d = (idx >> 18) & 1;
    int nt = q * 8 + wv;
    int n = nt * 16 + (lane & 15);
    int k = kt * 64 + ((lane >> 4) & 3) * 16 + j;
    int row = d * 1024 + n;
    float v0 = whh0[(size_t)row * 256 + k] * rsw0[row];
    float v1 = whh1[(size_t)row * 256 + k] * rsw1[row];
    wq0[idx] = (char)(int)fminf(fmaxf(rintf(v0), -127.f), 127.f);
    wq1[idx] = (char)(int)fminf(fmaxf(rintf(v1), -127.f), 127.f);
  }
  // fc frags: 16*64*8 = 8192 u16 (tags >= 9 zero-padded)
  for (int idx = tid; idx < 8192; idx += nth) {
    int j = idx & 7, lane = (idx >> 3) & 63, ks = (idx >> 9) & 15;
    int tag = lane & 15;
    int k = ks * 32 + ((lane >> 4) & 3) * 8 + j;
    fcfrag[idx] = (tag < Tn) ? f2bf(fcw[(size_t)tag * HIDn + k]) : (u16)0;
  }
  for (int idx = tid; idx < 2 * 1024; idx += nth) {
    bias0[idx] = bih0[idx] + bhh0[idx];
    bias1[idx] = bih1[idx] + bhh1[idx];
  }
}

// ---------------- MFMA input-projection GEMM -> gate-packed gx2[dir][m][unit][gate] ----------------
// v4: M-tile 128 (MT=8) — halves B-refetch, doubles MFMA per B-load vs v2. No prefetch
// double-buffer (R12 lesson: it thrashes L2). Gate-inner order + packed uint2 stores (v2).
// 1 block/CU (LDS 67/133 KB); __launch_bounds__(256,1) lifts VGPR cap to 512 (no spill).
template <int KS, bool GATHER>   // KS = K/32
__global__ __launch_bounds__(256, 1) void gemm_ih(
    const void* __restrict__ xsrc_v,   // GATHER: fp32 emb; else bf16 rows [M][512]
    const int* __restrict__ sent,
    const uint4* __restrict__ wifrag,  // [2][16][4][KS][64] uint4
    const float* __restrict__ bias,    // [2][1024]
    u16* __restrict__ gx2)             // [2*M][256][4] bf16
{
  constexpr int K = KS * 32;
  constexpr int PITCH = K + 8;        // u16; both 264 and 520 are 8 u16 = 16B multiples
  __shared__ u16 As[128][PITCH];
  const int tid = threadIdx.x;
  const int l = tid & 63;
  const int w = tid >> 6;
  const int col = l & 15;
  const int quad = (l >> 4) & 3;
  const int m0 = blockIdx.x * 128;
  const int dir = blockIdx.y;

  // stage A: 128 rows, 2 threads per row (lr = tid>>1, half lq = tid&1)
  {
    const int lr = tid >> 1, lq = tid & 1;
    if constexpr (GATHER) {
      const float4* xrow = reinterpret_cast<const float4*>(
          (const float*)xsrc_v + (size_t)sent[m0 + lr] * 256) + lq * 32;
      u32* dst = reinterpret_cast<u32*>(&As[lr][lq * 128]);
#pragma unroll
      for (int i = 0; i < 32; ++i) {
        float4 v = xrow[i];
        dst[i * 2 + 0] = (u32)f2bf(v.x) | ((u32)f2bf(v.y) << 16);
        dst[i * 2 + 1] = (u32)f2bf(v.z) | ((u32)f2bf(v.w) << 16);
      }
    } else {
      const uint4* xrow = reinterpret_cast<const uint4*>(
          (const u16*)xsrc_v + (size_t)(m0 + lr) * 512) + lq * 32;
      uint4* dst = reinterpret_cast<uint4*>(&As[lr][lq * 256]);
#pragma unroll
      for (int i = 0; i < 32; ++i) dst[i] = xrow[i];
    }
  }
  __syncthreads();

  const uint4* wfd = wifrag + (size_t)dir * 16 * 4 * KS * 64;
#pragma unroll 1
  for (int ub = 0; ub < 4; ++ub) {
    u32 pk0[8][4];   // gates 0,1 packed (i | f<<16) per [mt][r]
    u32 pk1[8][4];   // gates 2,3 packed (g | o<<16) per [mt][r]
#pragma unroll 1
    for (int gate = 0; gate < 4; ++gate) {
      const int nb = gate * 4 + ub;
      uint4 bf[KS];
#pragma unroll
      for (int ks = 0; ks < KS; ++ks)
        bf[ks] = wfd[((nb * 4 + w) * KS + ks) * 64 + l];

      f32x4 acc[8];
#pragma unroll
      for (int mt = 0; mt < 8; ++mt) acc[mt] = (f32x4){0.f, 0.f, 0.f, 0.f};
#pragma unroll
      for (int ks = 0; ks < KS; ++ks) {
        short8 b8 = __builtin_bit_cast(short8, bf[ks]);
#pragma unroll
        for (int mt = 0; mt < 8; ++mt) {
          uint4 av = *reinterpret_cast<const uint4*>(&As[mt * 16 + col][ks * 32 + quad * 8]);
          acc[mt] = __builtin_amdgcn_mfma_f32_16x16x32_bf16(
              __builtin_bit_cast(short8, av), b8, acc[mt], 0, 0, 0);
        }
      }

      const int n = nb * 64 + w * 16 + col;
      const float bv = bias[dir * 1024 + n];
#pragma unroll
      for (int mt = 0; mt < 8; ++mt) {
#pragma unroll
        for (int r = 0; r < 4; ++r) {
          u32 val = (u32)f2bf(acc[mt][r] + bv);
          if (gate == 0)      pk0[mt][r] = val;
          else if (gate == 1) pk0[mt][r] |= val << 16;
          else if (gate == 2) pk1[mt][r] = val;
          else                pk1[mt][r] |= val << 16;
        }
      }
    }
    // coalesced write: one uint2 per (m, unit)
    const int u = ub * 64 + w * 16 + col;
#pragma unroll
    for (int mt = 0; mt < 8; ++mt) {
#pragma unroll
      for (int r = 0; r < 4; ++r) {
        const int m = m0 + mt * 16 + quad * 4 + r;
        *reinterpret_cast<uint2*>(gx2 + ((size_t)(dir * Mn + m) * 256 + u) * 4) =
            (uint2){pk0[mt][r], pk1[mt][r]};
      }
    }
  }
}

// ---------------- MFMA recurrence v12 (proven 531 us): 2-row blocks, wave-local handoff ----
__global__ __launch_bounds__(512, 2) void lstm_recur_v12(
    const i32x4* __restrict__ wq,     // [2][8][8][4][64] i32x4
    const float* __restrict__ dqs,    // [2][1024]
    const u16* __restrict__ gx2,      // [2*Mn][256][4] bf16
    u16* __restrict__ out)            // [B][S][512] bf16
{
  __shared__ char Ah8[2][2][288];     // dbuf int8 h tile [2 rows][256 units], padded pitch
  __shared__ int accW[8][2][32][4];   // per-wave raw i32 acc [wave][row][unit-idx][gate]
  const int tid = threadIdx.x;
  const int l = tid & 63;
  const int w = tid >> 6;             // wave 0..7
  const int col = l & 15;
  const int quad = (l >> 4) & 3;
  const int dir = blockIdx.x >> 5;
  const int bq = blockIdx.x & 31;

  // ---- int8 recurrent weights into registers: 32 x i32x4 per lane ----
  i32x4 bw[8][4];
  {
    const i32x4* wp = wq + ((size_t)dir * 8 + w) * 8 * 4 * 64;
#pragma unroll
    for (int q = 0; q < 8; ++q)
#pragma unroll
      for (int kt = 0; kt < 4; ++kt)
        bw[q][kt] = wp[(q * 4 + kt) * 64 + l];
  }

  // epilogue task for this lane: row r_ep (0..1), unit-idx ue (0..31) within wave w
  const int r_ep = l >> 5;
  const int ue = l & 31;
  const int e_ep = ue >> 4, c_ep = ue & 15;
  const int unit = e_ep * 128 + w * 16 + c_ep;

  float sc[4];
#pragma unroll
  for (int g = 0; g < 4; ++g)
    sc[g] = dqs[dir * 1024 + g * 256 + unit];

  const int mrow = bq * 2 + r_ep;
  const uint2* gp = reinterpret_cast<const uint2*>(gx2) +
                    (size_t)(dir * Mn + mrow * Sn) * 256 + unit;
  u16* op = out + (size_t)mrow * Sn * HIDn + dir * Hn + unit;

  float c_st = 0.f;

  for (int s = 0; s < Sn; ++s) {
    const int t = dir ? (Sn - 1 - s) : s;
    uint2 g2 = gp[(size_t)t * 256];   // in flight across phases (lgkm-only barriers)

    if (s > 0) {
      const int rb = (s + 1) & 1;
      i32x4 av[4];
#pragma unroll
      for (int kt = 0; kt < 4; ++kt)
        av[kt] = *reinterpret_cast<const i32x4*>(
            &Ah8[rb][col & 1][kt * 64 + quad * 16]);
      i32x4 acc[8];
#pragma unroll
      for (int q = 0; q < 8; ++q) acc[q] = (i32x4){0, 0, 0, 0};
#pragma unroll
      for (int kt = 0; kt < 4; ++kt)
#pragma unroll
        for (int q = 0; q < 8; ++q)
          acc[q] = __builtin_amdgcn_mfma_i32_16x16x64_i8(av[kt], bw[q][kt], acc[q], 0, 0, 0);
      // wave-local scatter: quad0 lanes hold C rows 0..3; rows 0,1 are the real batch rows
      if (quad == 0) {
#pragma unroll
        for (int e = 0; e < 2; ++e)
#pragma unroll
          for (int r = 0; r < 2; ++r) {
            i32x4 v = (i32x4){acc[0 + e][r], acc[2 + e][r], acc[4 + e][r], acc[6 + e][r]};
            *reinterpret_cast<i32x4*>(&accW[w][r][e * 16 + col][0]) = v;
          }
      }
      // no barrier: same-wave LDS RAW ordered by lgkmcnt (compiler-inserted)
    }

    float a0 = 0.f, a1 = 0.f, a2 = 0.f, a3 = 0.f;
    if (s > 0) {
      i32x4 q0 = *reinterpret_cast<const i32x4*>(&accW[w][r_ep][ue][0]);
      a0 = (float)q0[0] * sc[0];
      a1 = (float)q0[1] * sc[1];
      a2 = (float)q0[2] * sc[2];
      a3 = (float)q0[3] * sc[3];
    }
    float gi_ = a0 + b2f((u16)(g2.x & 0xffff));
    float gf_ = a1 + b2f((u16)(g2.x >> 16));
    float gg_ = a2 + b2f((u16)(g2.y & 0xffff));
    float go_ = a3 + b2f((u16)(g2.y >> 16));

    c_st = sigf(gf_) * c_st + sigf(gi_) * tanh_f(gg_);
    float h = sigf(go_) * tanh_f(c_st);

    Ah8[s & 1][r_ep][unit] = (char)(int)rintf(h * 127.f);
    op[(size_t)t * HIDn] = f2bf(h);
    bar_lds();   // ONE barrier: h tile visible to all waves; out store stays in flight
  }
}

// ---------------- FC via MFMA: feats[bs][tag] = out1[bs] . fcw[tag] + fcb ----------------
__global__ __launch_bounds__(256) void fc_mfma(const u16* __restrict__ out1,
                                               const uint4* __restrict__ fcfrag, // [16][64]
                                               const float* __restrict__ fcb,
                                               float* __restrict__ feats) {
  __shared__ u16 As[64][520];
  const int tid = threadIdx.x;
  const int l = tid & 63;
  const int w = tid >> 6;
  const int col = l & 15;
  const int quad = (l >> 4) & 3;
  const int m0 = blockIdx.x * 64;

  {
    const int lr = tid >> 2, lq = tid & 3;
    const uint4* xrow = reinterpret_cast<const uint4*>(
        out1 + (size_t)(m0 + lr) * 512) + lq * 16;
    uint4* dst = reinterpret_cast<uint4*>(&As[lr][lq * 128]);
#pragma unroll
    for (int i = 0; i < 16; ++i) dst[i] = xrow[i];
  }
  __syncthreads();

  uint4 bf[16];
#pragma unroll
  for (int ks = 0; ks < 16; ++ks) bf[ks] = fcfrag[ks * 64 + l];

  f32x4 acc = (f32x4){0.f, 0.f, 0.f, 0.f};
#pragma unroll
  for (int ks = 0; ks < 16; ++ks) {
    uint4 av = *reinterpret_cast<const uint4*>(&As[w * 16 + col][ks * 32 + quad * 8]);
    acc = __builtin_amdgcn_mfma_f32_16x16x32_bf16(
        __builtin_bit_cast(short8, av), __builtin_bit_cast(short8, bf[ks]), acc, 0, 0, 0);
  }

  if (col < Tn) {
    const float bv = fcb[col];
#pragma unroll
    for (int r = 0; r < 4; ++r) {
      int m = m0 + w * 16 + quad * 4 + r;
      feats[(size_t)m * Tn + col] = acc[r] + bv;
    }
  }
}

// ---------------- CRF forward + gold, one wave per batch ----------------
__global__ __launch_bounds__(64) void crf_kernel(const float* __restrict__ feats,
                                                 const int* __restrict__ tags,
                                                 const int* __restrict__ lens,
                                                 const float* __restrict__ trans,
                                                 float* __restrict__ scores) {
  const int b = blockIdx.x;
  const int j = threadIdx.x;
  const int jj = j < Tn ? j : Tn - 1;
  const int len = lens[b];

  float trc[Tn];
#pragma unroll
  for (int i = 0; i < Tn; ++i) trc[i] = trans[i * Tn + jj];
  const float trS = trans[jj * Tn + STOP_T];

  float alpha = (j == START_T) ? 0.0f : NEGV;
  const float* fb = feats + (size_t)b * Sn * Tn;

  for (int t = 0; t < Sn; ++t) {
    float f = (j < Tn) ? fb[t * Tn + j] : 0.0f;
    float v[Tn];
    float m = -3.0e38f;
#pragma unroll
    for (int i = 0; i < Tn; ++i) {
      float ai = __shfl(alpha, i);
      v[i] = ai + trc[i];
      m = fmaxf(m, v[i]);
    }
    float ssum = 0.0f;
#pragma unroll
    for (int i = 0; i < Tn; ++i) ssum += __expf(v[i] - m);
    float newa = m + __logf(ssum) + f;
    if (t < len && j < Tn) alpha = newa;
  }

  float val = (j < Tn) ? alpha + trS : -3.0e38f;
  float m = val;
#pragma unroll
  for (int off = 32; off; off >>= 1) m = fmaxf(m, __shfl_xor(m, off));
  float se = (j < Tn) ? __expf(val - m) : 0.0f;
#pragma unroll
  for (int off = 32; off; off >>= 1) se += __shfl_xor(se, off);
  float fscore = m + __logf(se);

  const int* tg = tags + b * Sn;
  float part = 0.0f;
  for (int q = 0; q < 8; ++q) {
    int s0 = j * 8 + q;
    if (s0 < Sn - 1 && (s0 + 1) < len) {
      int ta = tg[s0], tb = tg[s0 + 1];
      part += trans[ta * Tn + tb] + fb[s0 * Tn + tb];
    }
  }
#pragma unroll
  for (int off = 32; off; off >>= 1) part += __shfl_xor(part, off);

  if (j == 0) {
    int t0 = tg[0];
    int tl = tg[len - 1];
    float gold = trans[START_T * Tn + t0] + fb[0 * Tn + t0] + part + trans[tl * Tn + STOP_T];
    scores[b] = fscore - gold;
  }
}

__global__ void finalize_kernel(const float* __restrict__ scores, float* __restrict__ out) {
  int l = threadIdx.x;
  float v = scores[l];
#pragma unroll
  for (int off = 32; off; off >>= 1) v += __shfl_xor(v, off);
  if (l == 0) out[0] = v / 64.0f;
}

extern "C" void kernel_launch(void* const* d_in, const int* in_sizes, int n_in,
                              void* d_out, int out_size, void* d_ws, size_t ws_size,
                              hipStream_t stream) {
  const int* sent = (const int*)d_in[0];
  const int* tags = (const int*)d_in[1];
  const int* lens = (const int*)d_in[2];
  const float* emb = (const float*)d_in[3];
  const float* wih0 = (const float*)d_in[4];
  const float* whh0 = (const float*)d_in[5];
  const float* bih0 = (const float*)d_in[6];
  const float* bhh0 = (const float*)d_in[7];
  const float* wih1 = (const float*)d_in[8];
  const float* whh1 = (const float*)d_in[9];
  const float* bih1 = (const float*)d_in[10];
  const float* bhh1 = (const float*)d_in[11];
  const float* fcw = (const float*)d_in[12];
  const float* fcb = (const float*)d_in[13];
  const float* trans = (const float*)d_in[14];

  // workspace (~172 MB)
  char* ws = (char*)d_ws;
  u16* outb = (u16*)ws;                                  // 33,554,432 B
  u16* gx2 = (u16*)(ws + 33554432);                      // 134,217,728 B
  float* feats = (float*)gx2;                            // aliases gx2 (dead before fc)
  char* p = ws + 33554432 + 134217728;
  float* scores = (float*)p;            p += 256;
  float* bias0 = (float*)p;             p += 8192;
  float* bias1 = (float*)p;             p += 8192;
  u16* wifrag0 = (u16*)p;               p += 1048576;    // 524,288 u16
  u16* wifrag1 = (u16*)p;               p += 2097152;    // 1,048,576 u16
  char* wq0 = p;                        p += 524288;     // int8 whh frags layer0
  char* wq1 = p;                        p += 524288;     // int8 whh frags layer1
  float* sw0 = (float*)p;               p += 8192;
  float* dqs0 = (float*)p;              p += 8192;
  float* sw1 = (float*)p;               p += 8192;
  float* dqs1 = (float*)p;              p += 8192;
  float* rsw0 = (float*)p;              p += 8192;
  float* rsw1 = (float*)p;              p += 8192;
  u16* fcfrag = (u16*)p;                p += 16384;      // 8192 u16

  prep_scales<<<512, 256, 0, stream>>>(whh0, whh1, sw0, dqs0, sw1, dqs1, rsw0, rsw1);
  prep_kernel<<<2048, 256, 0, stream>>>(wih0, whh0, bih0, bhh0, wih1, whh1, bih1, bhh1, fcw,
                                        wifrag0, wifrag1, wq0, wq1, rsw0, rsw1, bias0, bias1,
                                        fcfrag);

  dim3 ggrid(Mn / 128, 2);
  gemm_ih<8, true><<<ggrid, 256, 0, stream>>>(emb, sent, (const uint4*)wifrag0, bias0, gx2);
  lstm_recur_v12<<<64, 512, 0, stream>>>((const i32x4*)wq0, dqs0, gx2, outb);
  gemm_ih<16, false><<<ggrid, 256, 0, stream>>>(outb, nullptr, (const uint4*)wifrag1, bias1, gx2);
  lstm_recur_v12<<<64, 512, 0, stream>>>((const i32x4*)wq1, dqs1, gx2, outb);

  fc_mfma<<<Mn / 64, 256, 0, stream>>>(outb, (const uint4*)fcfrag, fcb, feats);
  crf_kernel<<<Bn, 64, 0, stream>>>(feats, tags, lens, trans, scores);
  finalize_kernel<<<1, 64, 0, stream>>>(scores, (float*)d_out);
}

// Round 14
// 1725.189 us; speedup vs baseline: 1.1623x; 1.1497x over previous
//
#include <hip/hip_runtime.h>
#include <math.h>

#define NEGV (-100000.0f)
constexpr int Bn = 64, Sn = 512, En = 256, Hn = 256, HIDn = 512, Tn = 9;
constexpr int START_T = Tn - 2, STOP_T = Tn - 1;
constexpr int Mn = Bn * Sn; // 32768 rows

typedef unsigned int u32;
typedef unsigned short u16;
typedef unsigned long long u64;
typedef short short8 __attribute__((ext_vector_type(8)));
typedef float f32x4 __attribute__((ext_vector_type(4)));
typedef int i32x4 __attribute__((ext_vector_type(4)));

__device__ __forceinline__ float sigf(float x) { return 1.0f / (1.0f + __expf(-x)); }
__device__ __forceinline__ float tanh_f(float x) { return 2.0f / (1.0f + __expf(-2.0f * x)) - 1.0f; }
__device__ __forceinline__ u16 f2bf(float f) {
  u32 u = __float_as_uint(f);
  return (u16)((u + 0x7fffu + ((u >> 16) & 1u)) >> 16);
}
__device__ __forceinline__ float bflo(u32 u) { return __uint_as_float(u << 16); }
__device__ __forceinline__ float bfhi(u32 u) { return __uint_as_float(u & 0xffff0000u); }
__device__ __forceinline__ float b2f(u16 v) { return __uint_as_float((u32)v << 16); }

// LDS-only workgroup barrier: does NOT drain vmcnt (global loads/stores stay in flight).
__device__ __forceinline__ void bar_lds() {
  __builtin_amdgcn_sched_barrier(0);
  asm volatile("s_waitcnt lgkmcnt(0)" ::: "memory");
  __builtin_amdgcn_s_barrier();
  __builtin_amdgcn_sched_barrier(0);
}

// ---------------- scales for int8 recurrent weights: one WAVE per gate-row ----------------
__global__ __launch_bounds__(256) void prep_scales(const float* __restrict__ whh0,
                                                   const float* __restrict__ whh1,
                                                   float* __restrict__ sw0, float* __restrict__ dqs0,
                                                   float* __restrict__ sw1, float* __restrict__ dqs1,
                                                   float* __restrict__ rsw0, float* __restrict__ rsw1) {
  const int gid = blockIdx.x * blockDim.x + threadIdx.x;
  const int row = gid >> 6;            // one wave per row
  const int lane = gid & 63;
  if (row >= 2048) return;
  float4 v0 = *reinterpret_cast<const float4*>(whh0 + (size_t)row * 256 + lane * 4);
  float4 v1 = *reinterpret_cast<const float4*>(whh1 + (size_t)row * 256 + lane * 4);
  float m0 = fmaxf(fmaxf(fabsf(v0.x), fabsf(v0.y)), fmaxf(fabsf(v0.z), fabsf(v0.w)));
  float m1 = fmaxf(fmaxf(fabsf(v1.x), fabsf(v1.y)), fmaxf(fabsf(v1.z), fabsf(v1.w)));
#pragma unroll
  for (int off = 32; off; off >>= 1) {
    m0 = fmaxf(m0, __shfl_xor(m0, off));
    m1 = fmaxf(m1, __shfl_xor(m1, off));
  }
  if (lane == 0) {
    m0 = fmaxf(m0, 1e-8f); m1 = fmaxf(m1, 1e-8f);
    sw0[row] = m0 / 127.f; dqs0[row] = m0 / (127.f * 127.f);
    sw1[row] = m1 / 127.f; dqs1[row] = m1 / (127.f * 127.f);
    rsw0[row] = 127.f / m0; rsw1[row] = 127.f / m1;
  }
}

// ---------------- prep: wih/fcw -> bf16 MFMA B-frags; whh -> int8 MFMA B-frags ----------------
__global__ void prep_kernel(const float* __restrict__ wih0, const float* __restrict__ whh0,
                            const float* __restrict__ bih0, const float* __restrict__ bhh0,
                            const float* __restrict__ wih1, const float* __restrict__ whh1,
                            const float* __restrict__ bih1, const float* __restrict__ bhh1,
                            const float* __restrict__ fcw,
                            u16* __restrict__ wifrag0, u16* __restrict__ wifrag1,
                            char* __restrict__ wq0, char* __restrict__ wq1,
                            const float* __restrict__ rsw0, const float* __restrict__ rsw1,
                            float* __restrict__ bias0, float* __restrict__ bias1,
                            u16* __restrict__ fcfrag) {
  int tid = blockIdx.x * blockDim.x + threadIdx.x;
  int nth = gridDim.x * blockDim.x;
  for (int idx = tid; idx < 524288; idx += nth) {
    int j = idx & 7, lane = (idx >> 3) & 63, ks = (idx >> 9) & 7,
        w2 = (idx >> 12) & 3, nb = (idx >> 14) & 15, d = (idx >> 18) & 1;
    int n = nb * 64 + w2 * 16 + (lane & 15);
    int k = ks * 32 + ((lane >> 4) & 3) * 8 + j;
    wifrag0[idx] = f2bf(wih0[(d * 1024 + n) * 256 + k]);
  }
  for (int idx = tid; idx < 1048576; idx += nth) {
    int j = idx & 7, lane = (idx >> 3) & 63, ks = (idx >> 9) & 15,
        w2 = (idx >> 13) & 3, nb = (idx >> 15) & 15, d = (idx >> 19) & 1;
    int n = nb * 64 + w2 * 16 + (lane & 15);
    int k = ks * 32 + ((lane >> 4) & 3) * 8 + j;
    wifrag1[idx] = f2bf(wih1[(d * 1024 + n) * 512 + k]);
  }
  // whh int8 frags: [d][w][q][kt][lane][j]
  for (int idx = tid; idx < 524288; idx += nth) {
    int j = idx & 15, lane = (idx >> 4) & 63, kt = (idx >> 10) & 3,
        q = (idx >> 12) & 7, wv = (idx >> 15) & 7, d = (idx >> 18) & 1;
    int nt = q * 8 + wv;
    int n = nt * 16 + (lane & 15);
    int k = kt * 64 + ((lane >> 4) & 3) * 16 + j;
    int row = d * 1024 + n;
    float v0 = whh0[(size_t)row * 256 + k] * rsw0[row];
    float v1 = whh1[(size_t)row * 256 + k] * rsw1[row];
    wq0[idx] = (char)(int)fminf(fmaxf(rintf(v0), -127.f), 127.f);
    wq1[idx] = (char)(int)fminf(fmaxf(rintf(v1), -127.f), 127.f);
  }
  // fc frags: 16*64*8 = 8192 u16 (tags >= 9 zero-padded)
  for (int idx = tid; idx < 8192; idx += nth) {
    int j = idx & 7, lane = (idx >> 3) & 63, ks = (idx >> 9) & 15;
    int tag = lane & 15;
    int k = ks * 32 + ((lane >> 4) & 3) * 8 + j;
    fcfrag[idx] = (tag < Tn) ? f2bf(fcw[(size_t)tag * HIDn + k]) : (u16)0;
  }
  for (int idx = tid; idx < 2 * 1024; idx += nth) {
    bias0[idx] = bih0[idx] + bhh0[idx];
    bias1[idx] = bih1[idx] + bhh1[idx];
  }
}

// ---------------- MFMA input-projection GEMM -> gate-packed gx2[dir][m][unit][gate] ----------------
// v2 structure (best measured) + dir-by-XCD-parity swizzle: 1D grid, dir = bid&1 so each
// XCD's resident blocks share ONE dir's B-fragment set (halves per-XCD L2 working set).
// ub-outer/gate-inner; 4 gates packed in regs; one coalesced uint2 store per (m,unit).
template <int KS, bool GATHER>   // KS = K/32
__global__ __launch_bounds__(256) void gemm_ih(
    const void* __restrict__ xsrc_v,   // GATHER: fp32 emb; else bf16 rows [M][512]
    const int* __restrict__ sent,
    const uint4* __restrict__ wifrag,  // [2][16][4][KS][64] uint4
    const float* __restrict__ bias,    // [2][1024]
    u16* __restrict__ gx2)             // [2*M][256][4] bf16
{
  constexpr int K = KS * 32;
  constexpr int PITCH = K + 8;
  __shared__ u16 As[64][PITCH];
  const int tid = threadIdx.x;
  const int l = tid & 63;
  const int w = tid >> 6;
  const int col = l & 15;
  const int quad = (l >> 4) & 3;
  const int bid = blockIdx.x;
  const int dir = bid & 1;           // XCD parity split: dir0 on even XCDs, dir1 on odd
  const int m0 = (bid >> 1) * 64;

  {
    const int lr = tid >> 2, lq = tid & 3;
    if constexpr (GATHER) {
      const float4* xrow = reinterpret_cast<const float4*>(
          (const float*)xsrc_v + (size_t)sent[m0 + lr] * 256) + lq * 16;
      u32* dst = reinterpret_cast<u32*>(&As[lr][lq * 64]);
#pragma unroll
      for (int i = 0; i < 16; ++i) {
        float4 v = xrow[i];
        dst[i * 2 + 0] = (u32)f2bf(v.x) | ((u32)f2bf(v.y) << 16);
        dst[i * 2 + 1] = (u32)f2bf(v.z) | ((u32)f2bf(v.w) << 16);
      }
    } else {
      const uint4* xrow = reinterpret_cast<const uint4*>(
          (const u16*)xsrc_v + (size_t)(m0 + lr) * 512) + lq * 16;
      uint4* dst = reinterpret_cast<uint4*>(&As[lr][lq * 128]);
#pragma unroll
      for (int i = 0; i < 16; ++i) dst[i] = xrow[i];
    }
  }
  __syncthreads();

  const uint4* wfd = wifrag + (size_t)dir * 16 * 4 * KS * 64;
#pragma unroll 1
  for (int ub = 0; ub < 4; ++ub) {
    u32 pk0[4][4];   // gates 0,1 packed (i | f<<16) per [mt][r]
    u32 pk1[4][4];   // gates 2,3 packed (g | o<<16) per [mt][r]
#pragma unroll 1
    for (int gate = 0; gate < 4; ++gate) {
      const int nb = gate * 4 + ub;
      uint4 bf[KS];
#pragma unroll
      for (int ks = 0; ks < KS; ++ks)
        bf[ks] = wfd[((nb * 4 + w) * KS + ks) * 64 + l];

      f32x4 acc[4];
#pragma unroll
      for (int mt = 0; mt < 4; ++mt) acc[mt] = (f32x4){0.f, 0.f, 0.f, 0.f};
#pragma unroll
      for (int ks = 0; ks < KS; ++ks) {
        short8 b8 = __builtin_bit_cast(short8, bf[ks]);
#pragma unroll
        for (int mt = 0; mt < 4; ++mt) {
          uint4 av = *reinterpret_cast<const uint4*>(&As[mt * 16 + col][ks * 32 + quad * 8]);
          acc[mt] = __builtin_amdgcn_mfma_f32_16x16x32_bf16(
              __builtin_bit_cast(short8, av), b8, acc[mt], 0, 0, 0);
        }
      }

      const int n = nb * 64 + w * 16 + col;
      const float bv = bias[dir * 1024 + n];
#pragma unroll
      for (int mt = 0; mt < 4; ++mt) {
#pragma unroll
        for (int r = 0; r < 4; ++r) {
          u32 val = (u32)f2bf(acc[mt][r] + bv);
          if (gate == 0)      pk0[mt][r] = val;
          else if (gate == 1) pk0[mt][r] |= val << 16;
          else if (gate == 2) pk1[mt][r] = val;
          else                pk1[mt][r] |= val << 16;
        }
      }
    }
    // coalesced write: one uint2 per (m, unit)
    const int u = ub * 64 + w * 16 + col;
#pragma unroll
    for (int mt = 0; mt < 4; ++mt) {
#pragma unroll
      for (int r = 0; r < 4; ++r) {
        const int m = m0 + mt * 16 + quad * 4 + r;
        *reinterpret_cast<uint2*>(gx2 + ((size_t)(dir * Mn + m) * 256 + u) * 4) =
            (uint2){pk0[mt][r], pk1[mt][r]};
      }
    }
  }
}

// ---------------- MFMA recurrence v12 (proven 531 us): 2-row blocks, wave-local handoff ----
__global__ __launch_bounds__(512, 2) void lstm_recur_v12(
    const i32x4* __restrict__ wq,     // [2][8][8][4][64] i32x4
    const float* __restrict__ dqs,    // [2][1024]
    const u16* __restrict__ gx2,      // [2*Mn][256][4] bf16
    u16* __restrict__ out)            // [B][S][512] bf16
{
  __shared__ char Ah8[2][2][288];     // dbuf int8 h tile [2 rows][256 units], padded pitch
  __shared__ int accW[8][2][32][4];   // per-wave raw i32 acc [wave][row][unit-idx][gate]
  const int tid = threadIdx.x;
  const int l = tid & 63;
  const int w = tid >> 6;             // wave 0..7
  const int col = l & 15;
  const int quad = (l >> 4) & 3;
  const int dir = blockIdx.x >> 5;
  const int bq = blockIdx.x & 31;

  // ---- int8 recurrent weights into registers: 32 x i32x4 per lane ----
  i32x4 bw[8][4];
  {
    const i32x4* wp = wq + ((size_t)dir * 8 + w) * 8 * 4 * 64;
#pragma unroll
    for (int q = 0; q < 8; ++q)
#pragma unroll
      for (int kt = 0; kt < 4; ++kt)
        bw[q][kt] = wp[(q * 4 + kt) * 64 + l];
  }

  // epilogue task for this lane: row r_ep (0..1), unit-idx ue (0..31) within wave w
  const int r_ep = l >> 5;
  const int ue = l & 31;
  const int e_ep = ue >> 4, c_ep = ue & 15;
  const int unit = e_ep * 128 + w * 16 + c_ep;

  float sc[4];
#pragma unroll
  for (int g = 0; g < 4; ++g)
    sc[g] = dqs[dir * 1024 + g * 256 + unit];

  const int mrow = bq * 2 + r_ep;
  const uint2* gp = reinterpret_cast<const uint2*>(gx2) +
                    (size_t)(dir * Mn + mrow * Sn) * 256 + unit;
  u16* op = out + (size_t)mrow * Sn * HIDn + dir * Hn + unit;

  float c_st = 0.f;

  for (int s = 0; s < Sn; ++s) {
    const int t = dir ? (Sn - 1 - s) : s;
    uint2 g2 = gp[(size_t)t * 256];   // in flight across phases (lgkm-only barriers)

    if (s > 0) {
      const int rb = (s + 1) & 1;
      i32x4 av[4];
#pragma unroll
      for (int kt = 0; kt < 4; ++kt)
        av[kt] = *reinterpret_cast<const i32x4*>(
            &Ah8[rb][col & 1][kt * 64 + quad * 16]);
      i32x4 acc[8];
#pragma unroll
      for (int q = 0; q < 8; ++q) acc[q] = (i32x4){0, 0, 0, 0};
#pragma unroll
      for (int kt = 0; kt < 4; ++kt)
#pragma unroll
        for (int q = 0; q < 8; ++q)
          acc[q] = __builtin_amdgcn_mfma_i32_16x16x64_i8(av[kt], bw[q][kt], acc[q], 0, 0, 0);
      // wave-local scatter: quad0 lanes hold C rows 0..3; rows 0,1 are the real batch rows
      if (quad == 0) {
#pragma unroll
        for (int e = 0; e < 2; ++e)
#pragma unroll
          for (int r = 0; r < 2; ++r) {
            i32x4 v = (i32x4){acc[0 + e][r], acc[2 + e][r], acc[4 + e][r], acc[6 + e][r]};
            *reinterpret_cast<i32x4*>(&accW[w][r][e * 16 + col][0]) = v;
          }
      }
      // no barrier: same-wave LDS RAW ordered by lgkmcnt (compiler-inserted)
    }

    float a0 = 0.f, a1 = 0.f, a2 = 0.f, a3 = 0.f;
    if (s > 0) {
      i32x4 q0 = *reinterpret_cast<const i32x4*>(&accW[w][r_ep][ue][0]);
      a0 = (float)q0[0] * sc[0];
      a1 = (float)q0[1] * sc[1];
      a2 = (float)q0[2] * sc[2];
      a3 = (float)q0[3] * sc[3];
    }
    float gi_ = a0 + b2f((u16)(g2.x & 0xffff));
    float gf_ = a1 + b2f((u16)(g2.x >> 16));
    float gg_ = a2 + b2f((u16)(g2.y & 0xffff));
    float go_ = a3 + b2f((u16)(g2.y >> 16));

    c_st = sigf(gf_) * c_st + sigf(gi_) * tanh_f(gg_);
    float h = sigf(go_) * tanh_f(c_st);

    Ah8[s & 1][r_ep][unit] = (char)(int)rintf(h * 127.f);
    op[(size_t)t * HIDn] = f2bf(h);
    bar_lds();   // ONE barrier: h tile visible to all waves; out store stays in flight
  }
}

// ---------------- FC via MFMA: feats[bs][tag] = out1[bs] . fcw[tag] + fcb ----------------
__global__ __launch_bounds__(256) void fc_mfma(const u16* __restrict__ out1,
                                               const uint4* __restrict__ fcfrag, // [16][64]
                                               const float* __restrict__ fcb,
                                               float* __restrict__ feats) {
  __shared__ u16 As[64][520];
  const int tid = threadIdx.x;
  const int l = tid & 63;
  const int w = tid >> 6;
  const int col = l & 15;
  const int quad = (l >> 4) & 3;
  const int m0 = blockIdx.x * 64;

  {
    const int lr = tid >> 2, lq = tid & 3;
    const uint4* xrow = reinterpret_cast<const uint4*>(
        out1 + (size_t)(m0 + lr) * 512) + lq * 16;
    uint4* dst = reinterpret_cast<uint4*>(&As[lr][lq * 128]);
#pragma unroll
    for (int i = 0; i < 16; ++i) dst[i] = xrow[i];
  }
  __syncthreads();

  uint4 bf[16];
#pragma unroll
  for (int ks = 0; ks < 16; ++ks) bf[ks] = fcfrag[ks * 64 + l];

  f32x4 acc = (f32x4){0.f, 0.f, 0.f, 0.f};
#pragma unroll
  for (int ks = 0; ks < 16; ++ks) {
    uint4 av = *reinterpret_cast<const uint4*>(&As[w * 16 + col][ks * 32 + quad * 8]);
    acc = __builtin_amdgcn_mfma_f32_16x16x32_bf16(
        __builtin_bit_cast(short8, av), __builtin_bit_cast(short8, bf[ks]), acc, 0, 0, 0);
  }

  if (col < Tn) {
    const float bv = fcb[col];
#pragma unroll
    for (int r = 0; r < 4; ++r) {
      int m = m0 + w * 16 + quad * 4 + r;
      feats[(size_t)m * Tn + col] = acc[r] + bv;
    }
  }
}

// ---------------- CRF forward + gold, one wave per batch ----------------
__global__ __launch_bounds__(64) void crf_kernel(const float* __restrict__ feats,
                                                 const int* __restrict__ tags,
                                                 const int* __restrict__ lens,
                                                 const float* __restrict__ trans,
                                                 float* __restrict__ scores) {
  const int b = blockIdx.x;
  const int j = threadIdx.x;
  const int jj = j < Tn ? j : Tn - 1;
  const int len = lens[b];

  float trc[Tn];
#pragma unroll
  for (int i = 0; i < Tn; ++i) trc[i] = trans[i * Tn + jj];
  const float trS = trans[jj * Tn + STOP_T];

  float alpha = (j == START_T) ? 0.0f : NEGV;
  const float* fb = feats + (size_t)b * Sn * Tn;

  for (int t = 0; t < Sn; ++t) {
    float f = (j < Tn) ? fb[t * Tn + j] : 0.0f;
    float v[Tn];
    float m = -3.0e38f;
#pragma unroll
    for (int i = 0; i < Tn; ++i) {
      float ai = __shfl(alpha, i);
      v[i] = ai + trc[i];
      m = fmaxf(m, v[i]);
    }
    float ssum = 0.0f;
#pragma unroll
    for (int i = 0; i < Tn; ++i) ssum += __expf(v[i] - m);
    float newa = m + __logf(ssum) + f;
    if (t < len && j < Tn) alpha = newa;
  }

  float val = (j < Tn) ? alpha + trS : -3.0e38f;
  float m = val;
#pragma unroll
  for (int off = 32; off; off >>= 1) m = fmaxf(m, __shfl_xor(m, off));
  float se = (j < Tn) ? __expf(val - m) : 0.0f;
#pragma unroll
  for (int off = 32; off; off >>= 1) se += __shfl_xor(se, off);
  float fscore = m + __logf(se);

  const int* tg = tags + b * Sn;
  float part = 0.0f;
  for (int q = 0; q < 8; ++q) {
    int s0 = j * 8 + q;
    if (s0 < Sn - 1 && (s0 + 1) < len) {
      int ta = tg[s0], tb = tg[s0 + 1];
      part += trans[ta * Tn + tb] + fb[s0 * Tn + tb];
    }
  }
#pragma unroll
  for (int off = 32; off; off >>= 1) part += __shfl_xor(part, off);

  if (j == 0) {
    int t0 = tg[0];
    int tl = tg[len - 1];
    float gold = trans[START_T * Tn + t0] + fb[0 * Tn + t0] + part + trans[tl * Tn + STOP_T];
    scores[b] = fscore - gold;
  }
}

__global__ void finalize_kernel(const float* __restrict__ scores, float* __restrict__ out) {
  int l = threadIdx.x;
  float v = scores[l];
#pragma unroll
  for (int off = 32; off; off >>= 1) v += __shfl_xor(v, off);
  if (l == 0) out[0] = v / 64.0f;
}

extern "C" void kernel_launch(void* const* d_in, const int* in_sizes, int n_in,
                              void* d_out, int out_size, void* d_ws, size_t ws_size,
                              hipStream_t stream) {
  const int* sent = (const int*)d_in[0];
  const int* tags = (const int*)d_in[1];
  const int* lens = (const int*)d_in[2];
  const float* emb = (const float*)d_in[3];
  const float* wih0 = (const float*)d_in[4];
  const float* whh0 = (const float*)d_in[5];
  const float* bih0 = (const float*)d_in[6];
  const float* bhh0 = (const float*)d_in[7];
  const float* wih1 = (const float*)d_in[8];
  const float* whh1 = (const float*)d_in[9];
  const float* bih1 = (const float*)d_in[10];
  const float* bhh1 = (const float*)d_in[11];
  const float* fcw = (const float*)d_in[12];
  const float* fcb = (const float*)d_in[13];
  const float* trans = (const float*)d_in[14];

  // workspace (~172 MB)
  char* ws = (char*)d_ws;
  u16* outb = (u16*)ws;                                  // 33,554,432 B
  u16* gx2 = (u16*)(ws + 33554432);                      // 134,217,728 B
  float* feats = (float*)gx2;                            // aliases gx2 (dead before fc)
  char* p = ws + 33554432 + 134217728;
  float* scores = (float*)p;            p += 256;
  float* bias0 = (float*)p;             p += 8192;
  float* bias1 = (float*)p;             p += 8192;
  u16* wifrag0 = (u16*)p;               p += 1048576;    // 524,288 u16
  u16* wifrag1 = (u16*)p;               p += 2097152;    // 1,048,576 u16
  char* wq0 = p;                        p += 524288;     // int8 whh frags layer0
  char* wq1 = p;                        p += 524288;     // int8 whh frags layer1
  float* sw0 = (float*)p;               p += 8192;
  float* dqs0 = (float*)p;              p += 8192;
  float* sw1 = (float*)p;               p += 8192;
  float* dqs1 = (float*)p;              p += 8192;
  float* rsw0 = (float*)p;              p += 8192;
  float* rsw1 = (float*)p;              p += 8192;
  u16* fcfrag = (u16*)p;                p += 16384;      // 8192 u16

  prep_scales<<<512, 256, 0, stream>>>(whh0, whh1, sw0, dqs0, sw1, dqs1, rsw0, rsw1);
  prep_kernel<<<2048, 256, 0, stream>>>(wih0, whh0, bih0, bhh0, wih1, whh1, bih1, bhh1, fcw,
                                        wifrag0, wifrag1, wq0, wq1, rsw0, rsw1, bias0, bias1,
                                        fcfrag);

  gemm_ih<8, true><<<(Mn / 64) * 2, 256, 0, stream>>>(emb, sent, (const uint4*)wifrag0, bias0, gx2);
  lstm_recur_v12<<<64, 512, 0, stream>>>((const i32x4*)wq0, dqs0, gx2, outb);
  gemm_ih<16, false><<<(Mn / 64) * 2, 256, 0, stream>>>(outb, nullptr, (const uint4*)wifrag1, bias1, gx2);
  lstm_recur_v12<<<64, 512, 0, stream>>>((const i32x4*)wq1, dqs1, gx2, outb);

  fc_mfma<<<Mn / 64, 256, 0, stream>>>(outb, (const uint4*)fcfrag, fcb, feats);
  crf_kernel<<<Bn, 64, 0, stream>>>(feats, tags, lens, trans, scores);
  finalize_kernel<<<1, 64, 0, stream>>>(scores, (float*)d_out);
}